// Round 14
// baseline (758.550 us; speedup 1.0000x reference)
//
#include <hip/hip_runtime.h>

#define BB 4
#define NFINE 200000
#define NC 50000
#define CH 32
#define NPOOL 200000
#define NEDGE 800000
#define EPSV 1e-5f
#define NWAVES 8192   // 2048 blocks * 4 waves/block (grid-stride kernels)
#define NCHUNK 49     // ceil(NC / 1024)

__device__ __forceinline__ int rfl(int v) { return __builtin_amdgcn_readfirstlane(v); }

// ---------------- broadcast lane K within each 32-lane group ----------------
template<int K>
__device__ __forceinline__ float2 bcast2(float2 v) {
    union { float f; int i; } x, y;
    x.f = v.x; y.f = v.y;
    x.i = __builtin_amdgcn_ds_swizzle(x.i, (K << 5));   // BitMode: and=0, or=K
    y.i = __builtin_amdgcn_ds_swizzle(y.i, (K << 5));
    return make_float2(x.f, y.f);
}

// z += v[k]*wr[k], g += v[k]*wn[k] over k=0..K with shared broadcasts
template<int K>
struct MM2 {
    static __device__ __forceinline__ void run(const float2& v, const float* wr,
                                               const float* wn, float2& z, float2& g) {
        MM2<K - 1>::run(v, wr, wn, z, g);
        float2 vb = bcast2<K>(v);
        z.x += vb.x * wr[K]; z.y += vb.y * wr[K];
        g.x += vb.x * wn[K]; g.y += vb.y * wn[K];
    }
};
template<>
struct MM2<-1> {
    static __device__ __forceinline__ void run(const float2&, const float*,
                                               const float*, float2&, float2&) {}
};

// ---------------- zero ----------------
__global__ void zero_kernel(int* __restrict__ p, int n) {
    int i = blockIdx.x * blockDim.x + threadIdx.x;
    int stride = gridDim.x * blockDim.x;
    for (; i < n; i += stride) p[i] = 0;
}

// ---------------- histogram ----------------
__global__ void hist_kernel(const int* __restrict__ dst, int n, int* __restrict__ cnt) {
    int i = blockIdx.x * blockDim.x + threadIdx.x;
    int stride = gridDim.x * blockDim.x;
    for (; i < n; i += stride) atomicAdd(&cnt[dst[i]], 1);
}

// ---------------- device-wide exclusive scan, phase 1: per-chunk sums ------
__global__ __launch_bounds__(1024)
void chunk_sum_kernel(const int* __restrict__ cntP, const int* __restrict__ cntE,
                      int* __restrict__ scanTmp) {
    __shared__ int lds[1024];
    const int* __restrict__ cnt = blockIdx.y ? cntE : cntP;
    int* csum = scanTmp + (blockIdx.y ? 64 : 0);
    const int j = blockIdx.x, t = threadIdx.x;
    const int idx = j * 1024 + t;
    lds[t] = (idx < NC) ? cnt[idx] : 0;
    __syncthreads();
    for (int off = 512; off > 0; off >>= 1) {
        if (t < off) lds[t] += lds[t + off];
        __syncthreads();
    }
    if (t == 0) csum[j] = lds[0];
}

// ---------------- phase 2: scan the NCHUNK chunk sums (one wave) ------------
__global__ void chunk_mid_kernel(int* __restrict__ scanTmp) {
    int* csum = scanTmp + (blockIdx.y ? 64 : 0);
    int* coff = scanTmp + (blockIdx.y ? 192 : 128);
    const int t = threadIdx.x;
    int v = (t < NCHUNK) ? csum[t] : 0;
    const int orig = v;
    for (int off = 1; off < 64; off <<= 1) {
        int u = __shfl_up(v, off, 64);
        if (t >= off) v += u;
    }
    if (t < NCHUNK) coff[t] = v - orig;   // exclusive chunk offset
}

// ---------------- phase 3: block scan within chunk + chunk offset -----------
__global__ __launch_bounds__(1024)
void chunk_scan_kernel(int* __restrict__ cntP, int* __restrict__ cntE,
                       const int* __restrict__ scanTmp,
                       int* __restrict__ rowpP, int* __restrict__ rowpE) {
    __shared__ int lds[1024];
    int* __restrict__ cnt = blockIdx.y ? cntE : cntP;
    const int* coff = scanTmp + (blockIdx.y ? 192 : 128);
    int* __restrict__ rowp = blockIdx.y ? rowpE : rowpP;
    const int j = blockIdx.x, t = threadIdx.x;
    const int idx = j * 1024 + t;
    const int v = (idx < NC) ? cnt[idx] : 0;
    lds[t] = v;
    __syncthreads();
    for (int off = 1; off < 1024; off <<= 1) {
        int u = (t >= off) ? lds[t - off] : 0;
        __syncthreads();
        lds[t] += u;
        __syncthreads();
    }
    const int excl = lds[t] - v + coff[j];
    if (idx < NC) {
        rowp[idx] = excl;
        cnt[idx] = excl;        // scatter cursor
    }
    if (idx == NC - 1) rowp[NC] = excl + v;
}

// ---------------- scatter into CSR (packed src+weight, one 8B store/edge) ----
__global__ void scatter_kernel(const int* __restrict__ src, const int* __restrict__ dst,
                               const float* __restrict__ attr, int n,
                               int* __restrict__ next, int2* __restrict__ pk) {
    int i = blockIdx.x * blockDim.x + threadIdx.x;
    int stride = gridDim.x * blockDim.x;
    for (; i < n; i += stride) {
        int d = dst[i];
        int pos = atomicAdd(&next[d], 1);
        pk[pos] = make_int2(src[i], __float_as_int(attr[i]));
    }
}

// ---------------- pool (plain, small-ws path) -------------------------------
__global__ __launch_bounds__(256)
void pool_kernel(const float* __restrict__ x, float* __restrict__ pooled,
                 const int* __restrict__ rowp, const int2* __restrict__ pk) {
    const int tid = threadIdx.x;
    const int lane = tid & 63;
    const int c = lane & 31;
    const int bh = lane >> 5;
    const int n = blockIdx.x * 4 + (tid >> 6);
    if (n >= NC) return;
    const float* __restrict__ xA = x + (size_t)(2 * bh) * NFINE * CH;
    const float* __restrict__ xB = x + (size_t)(2 * bh + 1) * NFINE * CH;
    int e0 = rfl(rowp[n]), e1 = rfl(rowp[n + 1]);
    float2 a0 = {0, 0}, a1 = {0, 0}, a2 = {0, 0}, a3 = {0, 0};
    int e = e0;
    for (; e + 4 <= e1; e += 4) {
        int2 p0 = pk[e], p1 = pk[e + 1], p2 = pk[e + 2], p3 = pk[e + 3];
        float w0 = __int_as_float(p0.y), w1 = __int_as_float(p1.y);
        float w2 = __int_as_float(p2.y), w3 = __int_as_float(p3.y);
        a0.x += w0 * xA[p0.x * CH + c]; a0.y += w0 * xB[p0.x * CH + c];
        a1.x += w1 * xA[p1.x * CH + c]; a1.y += w1 * xB[p1.x * CH + c];
        a2.x += w2 * xA[p2.x * CH + c]; a2.y += w2 * xB[p2.x * CH + c];
        a3.x += w3 * xA[p3.x * CH + c]; a3.y += w3 * xB[p3.x * CH + c];
    }
    for (; e < e1; ++e) {
        int2 p0 = pk[e];
        float w0 = __int_as_float(p0.y);
        a0.x += w0 * xA[p0.x * CH + c];
        a0.y += w0 * xB[p0.x * CH + c];
    }
    ((float2*)pooled)[(n * CH + c) * 2 + bh] =
        make_float2((a0.x + a1.x) + (a2.x + a3.x), (a0.y + a1.y) + (a2.y + a3.y));
}

// ---------------- fused pool + dense1: x -> z1, g1 --------------------------
__global__ __launch_bounds__(256)
void pool_dense_kernel(const float* __restrict__ x, float* __restrict__ zout,
                       float* __restrict__ gout,
                       const int* __restrict__ rowp, const int2* __restrict__ pk,
                       const float* __restrict__ Wr, const float* __restrict__ Wn,
                       const float* __restrict__ bias) {
    const int tid = threadIdx.x;
    const int lane = tid & 63;
    const int c = lane & 31;
    const int bh = lane >> 5;
    const int n = blockIdx.x * 4 + (tid >> 6);
    if (n >= NC) return;
    float wr[CH], wn[CH];
#pragma unroll
    for (int k = 0; k < CH; ++k) {
        wr[k] = Wr[k * CH + c];
        wn[k] = Wn[k * CH + c];
    }
    const float bc = bias[c];
    const float* __restrict__ xA = x + (size_t)(2 * bh) * NFINE * CH;
    const float* __restrict__ xB = x + (size_t)(2 * bh + 1) * NFINE * CH;
    int e0 = rfl(rowp[n]), e1 = rfl(rowp[n + 1]);
    float2 a0 = {0, 0}, a1 = {0, 0}, a2 = {0, 0}, a3 = {0, 0};
    int e = e0;
    for (; e + 4 <= e1; e += 4) {
        int2 p0 = pk[e], p1 = pk[e + 1], p2 = pk[e + 2], p3 = pk[e + 3];
        float w0 = __int_as_float(p0.y), w1 = __int_as_float(p1.y);
        float w2 = __int_as_float(p2.y), w3 = __int_as_float(p3.y);
        a0.x += w0 * xA[p0.x * CH + c]; a0.y += w0 * xB[p0.x * CH + c];
        a1.x += w1 * xA[p1.x * CH + c]; a1.y += w1 * xB[p1.x * CH + c];
        a2.x += w2 * xA[p2.x * CH + c]; a2.y += w2 * xB[p2.x * CH + c];
        a3.x += w3 * xA[p3.x * CH + c]; a3.y += w3 * xB[p3.x * CH + c];
    }
    for (; e < e1; ++e) {
        int2 p0 = pk[e];
        float w0 = __int_as_float(p0.y);
        a0.x += w0 * xA[p0.x * CH + c];
        a0.y += w0 * xB[p0.x * CH + c];
    }
    float2 pooled = make_float2((a0.x + a1.x) + (a2.x + a3.x),
                                (a0.y + a1.y) + (a2.y + a3.y));
    float2 z = {bc, bc}, g = {0.f, 0.f};
    MM2<CH - 1>::run(pooled, wr, wn, z, g);
    ((float2*)zout)[(n * CH + c) * 2 + bh] = z;
    ((float2*)gout)[(n * CH + c) * 2 + bh] = g;
}

// ---------------- fused gather(conv i) + dense(conv i+1) --------------------
// out = z[n] + sum w*g[src]; then z' = out@Wr' + b' (in-place), g' = out@Wn'
__global__ __launch_bounds__(256)
void gd_kernel(float* zio, const float* __restrict__ gin, float* __restrict__ gout,
               const int* __restrict__ rowp, const int2* __restrict__ pk,
               const float* __restrict__ Wr, const float* __restrict__ Wn,
               const float* __restrict__ bias) {
    const int tid = threadIdx.x;
    const int lane = tid & 63;
    const int c = lane & 31;
    const int bh = lane >> 5;
    const int n = blockIdx.x * 4 + (tid >> 6);
    if (n >= NC) return;
    float wr[CH], wn[CH];
#pragma unroll
    for (int k = 0; k < CH; ++k) {
        wr[k] = Wr[k * CH + c];
        wn[k] = Wn[k * CH + c];
    }
    const float bc = bias[c];

    const float2* __restrict__ g2 = (const float2*)gin;
    float2 acc = ((float2*)zio)[(n * CH + c) * 2 + bh];
    float2 ac1 = {0.f, 0.f};
    int e0 = rfl(rowp[n]), e1 = rfl(rowp[n + 1]);
    int e = e0;
    for (; e + 8 <= e1; e += 8) {
#pragma unroll
        for (int i = 0; i < 8; i += 2) {
            int2 p0 = pk[e + i], p1 = pk[e + i + 1];
            float w0 = __int_as_float(p0.y), w1 = __int_as_float(p1.y);
            float2 v0 = g2[(p0.x * CH + c) * 2 + bh];
            float2 v1 = g2[(p1.x * CH + c) * 2 + bh];
            acc.x += w0 * v0.x; acc.y += w0 * v0.y;
            ac1.x += w1 * v1.x; ac1.y += w1 * v1.y;
        }
    }
    for (; e < e1; ++e) {
        int2 p0 = pk[e];
        float w0 = __int_as_float(p0.y);
        float2 v0 = g2[(p0.x * CH + c) * 2 + bh];
        acc.x += w0 * v0.x; acc.y += w0 * v0.y;
    }
    acc.x += ac1.x; acc.y += ac1.y;

    float2 z = {bc, bc}, g = {0.f, 0.f};
    MM2<CH - 1>::run(acc, wr, wn, z, g);
    ((float2*)zio)[(n * CH + c) * 2 + bh] = z;
    ((float2*)gout)[(n * CH + c) * 2 + bh] = g;
}

// ---------------- dense pass (LDS staging), used for conv3 (norm) -----------
template<bool NORM>
__global__ __launch_bounds__(256)
void dense_kernel(const float* hin, float* zout, float* __restrict__ gout,
                  const float* __restrict__ Wr, const float* __restrict__ Wn,
                  const float* __restrict__ bias, const float* __restrict__ st) {
    __shared__ float2 stage[4][2][64];
    const int tid = threadIdx.x;
    const int lane = tid & 63;
    const int c = lane & 31;
    const int bh = lane >> 5;
    const int w = tid >> 6;
    const int wid = blockIdx.x * 4 + w;

    float wr[CH], wn[CH];
#pragma unroll
    for (int k = 0; k < CH; ++k) {
        wr[k] = Wr[k * CH + c];
        wn[k] = Wn[k * CH + c];
    }
    const float bc = bias[c];

    float2 rs = {1.f, 1.f}, mr = {0.f, 0.f};
    if constexpr (NORM) {
        float2 m2 = ((const float2*)(st + 256))[c * 2 + bh];
        rs = ((const float2*)(st + 384))[c * 2 + bh];
        mr = make_float2(m2.x * rs.x, m2.y * rs.y);
    }

    const float2* h2 = (const float2*)hin;
    int it = 0;
    for (int n = wid; n < NC; n += NWAVES, ++it) {
        float2 xv = h2[(n * CH + c) * 2 + bh];
        if constexpr (NORM) {
            xv.x = xv.x * rs.x - mr.x;
            xv.y = xv.y * rs.y - mr.y;
        }
        stage[w][it & 1][lane] = xv;
        float2 z = {bc, bc}, g = {0.f, 0.f};
#pragma unroll
        for (int k = 0; k < CH; ++k) {
            float2 v = stage[w][it & 1][bh * 32 + k];
            z.x += v.x * wr[k]; z.y += v.y * wr[k];
            g.x += v.x * wn[k]; g.y += v.y * wn[k];
        }
        ((float2*)zout)[(n * CH + c) * 2 + bh] = z;
        ((float2*)gout)[(n * CH + c) * 2 + bh] = g;
    }
}

// ---------------- gather pass (no fused dense) ------------------------------
template<bool OUTBNC>
__global__ __launch_bounds__(256)
void gather_kernel(const float* zin, const float* __restrict__ gin, float* hout,
                   const int* __restrict__ rowp, const int2* __restrict__ pk) {
    const int tid = threadIdx.x;
    const int lane = tid & 63;
    const int c = lane & 31;
    const int bh = lane >> 5;
    const int n = blockIdx.x * 4 + (tid >> 6);
    if (n >= NC) return;

    const float2* __restrict__ g2 = (const float2*)gin;
    float2 acc = ((const float2*)zin)[(n * CH + c) * 2 + bh];
    float2 ac1 = {0.f, 0.f};
    int e0 = rfl(rowp[n]), e1 = rfl(rowp[n + 1]);
    int e = e0;
    for (; e + 8 <= e1; e += 8) {
#pragma unroll
        for (int i = 0; i < 8; i += 2) {
            int2 p0 = pk[e + i], p1 = pk[e + i + 1];
            float w0 = __int_as_float(p0.y), w1 = __int_as_float(p1.y);
            float2 v0 = g2[(p0.x * CH + c) * 2 + bh];
            float2 v1 = g2[(p1.x * CH + c) * 2 + bh];
            acc.x += w0 * v0.x; acc.y += w0 * v0.y;
            ac1.x += w1 * v1.x; ac1.y += w1 * v1.y;
        }
    }
    for (; e < e1; ++e) {
        int2 p0 = pk[e];
        float w0 = __int_as_float(p0.y);
        float2 v0 = g2[(p0.x * CH + c) * 2 + bh];
        acc.x += w0 * v0.x; acc.y += w0 * v0.y;
    }
    acc.x += ac1.x; acc.y += ac1.y;
    if constexpr (OUTBNC) {
        hout[(size_t)(2 * bh + 0) * (NC * CH) + n * CH + c] = acc.x;
        hout[(size_t)(2 * bh + 1) * (NC * CH) + n * CH + c] = acc.y;
    } else {
        ((float2*)hout)[(n * CH + c) * 2 + bh] = acc;
    }
}

// ---------------- instance-norm stats over [N][CH][B] -----------------------
__global__ __launch_bounds__(256)
void stats_kernel(const float* __restrict__ h, float* __restrict__ st) {
    __shared__ float4 ls[256], lq[256];
    const int tid = threadIdx.x;
    float4 s = {0, 0, 0, 0}, q = {0, 0, 0, 0};
    const float4* __restrict__ h4 = (const float4*)h;
    const int total4 = NC * CH;
    const int stride = gridDim.x * blockDim.x;
    for (int i = blockIdx.x * blockDim.x + tid; i < total4; i += stride) {
        float4 v = h4[i];
        s.x += v.x; s.y += v.y; s.z += v.z; s.w += v.w;
        q.x += v.x * v.x; q.y += v.y * v.y; q.z += v.z * v.z; q.w += v.w * v.w;
    }
    ls[tid] = s; lq[tid] = q;
    __syncthreads();
    if (tid < 32) {
        float4 ts = ls[tid], tq = lq[tid];
#pragma unroll
        for (int g = 1; g < 8; ++g) {
            float4 o = ls[g * 32 + tid];
            ts.x += o.x; ts.y += o.y; ts.z += o.z; ts.w += o.w;
            float4 p = lq[g * 32 + tid];
            tq.x += p.x; tq.y += p.y; tq.z += p.z; tq.w += p.w;
        }
        atomicAdd(&st[tid * 4 + 0], ts.x);
        atomicAdd(&st[tid * 4 + 1], ts.y);
        atomicAdd(&st[tid * 4 + 2], ts.z);
        atomicAdd(&st[tid * 4 + 3], ts.w);
        atomicAdd(&st[128 + tid * 4 + 0], tq.x);
        atomicAdd(&st[128 + tid * 4 + 1], tq.y);
        atomicAdd(&st[128 + tid * 4 + 2], tq.z);
        atomicAdd(&st[128 + tid * 4 + 3], tq.w);
    }
}

__global__ void stats_fin(float* __restrict__ st) {
    int i = threadIdx.x;
    if (i < 128) {
        float m = st[i] * (1.f / NC);
        float v = st[128 + i] * (1.f / NC) - m * m;
        st[256 + i] = m;
        st[384 + i] = rsqrtf(v + EPSV);
    }
}

// ---------------- transpose NCB -> BNC (small-ws path bounce) ----------------
__global__ __launch_bounds__(256)
void transpose_kernel(const float* __restrict__ in, float* __restrict__ out) {
    const int tid = threadIdx.x;
    const int lane = tid & 63;
    const int c = lane & 31;
    const int bh = lane >> 5;
    const int n = blockIdx.x * 4 + (tid >> 6);
    if (n >= NC) return;
    float2 v = ((const float2*)in)[(n * CH + c) * 2 + bh];
    out[(size_t)(2 * bh + 0) * (NC * CH) + n * CH + c] = v.x;
    out[(size_t)(2 * bh + 1) * (NC * CH) + n * CH + c] = v.y;
}

extern "C" void kernel_launch(void* const* d_in, const int* in_sizes, int n_in,
                              void* d_out, int out_size, void* d_ws, size_t ws_size,
                              hipStream_t stream) {
    const float* x         = (const float*)d_in[0];
    const int*   pool_src  = (const int*)d_in[1];
    const int*   pool_dst  = (const int*)d_in[2];
    const float* pool_attr = (const float*)d_in[3];
    const int*   edge_src  = (const int*)d_in[4];
    const int*   edge_dst  = (const int*)d_in[5];
    const float* edge_attr = (const float*)d_in[6];
    const float* Wr1 = (const float*)d_in[8];
    const float* Wn1 = (const float*)d_in[9];
    const float* b1  = (const float*)d_in[10];
    const float* Wr2 = (const float*)d_in[11];
    const float* Wn2 = (const float*)d_in[12];
    const float* b2  = (const float*)d_in[13];
    const float* Wr3 = (const float*)d_in[14];
    const float* Wn3 = (const float*)d_in[15];
    const float* b3  = (const float*)d_in[16];
    const float* Wr4 = (const float*)d_in[17];
    const float* Wn4 = (const float*)d_in[18];
    const float* b4  = (const float*)d_in[19];

    const size_t BUFB = (size_t)NC * CH * BB * 4;   // 25,600,000 B
    const size_t CSRB = 2 * (size_t)(NC + 1) * 4 + 2 * (size_t)NC * 4 + 512 * 4 + 256 * 4
                        + (size_t)NPOOL * 8 + (size_t)NEDGE * 8;  // ~8.8 MB
    char* w = (char*)d_ws;
    const bool bigws = ws_size >= 2 * BUFB + CSRB + 1024;

    float* D = (float*)d_out;
    float* P;          // z-buffer (fused) / h ping (fallback)
    float* G;          // g-buffer A (fused) / bufA (fallback)
    if (bigws) {
        P = (float*)w;  w += BUFB;
        G = (float*)w;  w += BUFB;
    } else {
        G = (float*)w;  w += BUFB;
        P = D;
    }
    int*   poolRow  = (int*)w;  w += (size_t)(NC + 1) * 4;
    int*   edgeRow  = (int*)w;  w += (size_t)(NC + 1) * 4;
    int*   zbase    = (int*)w;                       // contiguous zero region:
    int*   poolNext = (int*)w;  w += (size_t)NC * 4;
    int*   edgeNext = (int*)w;  w += (size_t)NC * 4;
    float* stats    = (float*)w; w += 512 * 4;
    int*   scanTmp  = (int*)w;  w += 256 * 4;       // csumP|csumE|coffP|coffE
    int2*  poolPk   = (int2*)w; w += (size_t)NPOOL * 8;
    int2*  edgePk   = (int2*)w; w += (size_t)NEDGE * 8;

    const int ZN = NC + NC + 256;      // next cursors + stats sums/sumsq
    const int NB = (NC + 3) / 4;       // 12500 blocks, 1 node/wave

    // ---- CSR build (by dst; reused by all 4 convs) ----
    zero_kernel<<<98, 1024, 0, stream>>>(zbase, ZN);
    hist_kernel<<<782, 256, 0, stream>>>(pool_dst, NPOOL, poolNext);
    hist_kernel<<<3125, 256, 0, stream>>>(edge_dst, NEDGE, edgeNext);
    chunk_sum_kernel<<<dim3(NCHUNK, 2), 1024, 0, stream>>>(poolNext, edgeNext, scanTmp);
    chunk_mid_kernel<<<dim3(1, 2), 64, 0, stream>>>(scanTmp);
    chunk_scan_kernel<<<dim3(NCHUNK, 2), 1024, 0, stream>>>(poolNext, edgeNext, scanTmp,
                                                            poolRow, edgeRow);
    scatter_kernel<<<782, 256, 0, stream>>>(pool_src, pool_dst, pool_attr, NPOOL,
                                            poolNext, poolPk);
    scatter_kernel<<<3125, 256, 0, stream>>>(edge_src, edge_dst, edge_attr, NEDGE,
                                             edgeNext, edgePk);

    if (bigws) {
        // ---- fused pipeline: z lives in P (in-place), g ping-pongs G <-> D ----
        pool_dense_kernel<<<NB, 256, 0, stream>>>(x, P, G, poolRow, poolPk, Wr1, Wn1, b1);
        // conv1 gather + conv2 dense: (z1,g1) -> z2 (P), g2 (D)
        gd_kernel<<<NB, 256, 0, stream>>>(P, G, D, edgeRow, edgePk, Wr2, Wn2, b2);
        // conv2 gather: (z2,g2) -> h2 (G)
        gather_kernel<false><<<NB, 256, 0, stream>>>(P, D, G, edgeRow, edgePk);
        stats_kernel<<<200, 256, 0, stream>>>(G, stats);
        stats_fin<<<1, 128, 0, stream>>>(stats);
        // conv3 dense (normalized): h2 (G) -> z3 (P), g3 (D)
        dense_kernel<true><<<2048, 256, 0, stream>>>(G, P, D, Wr3, Wn3, b3, stats);
        // conv3 gather + conv4 dense: -> z4 (P), g4 (G)
        gd_kernel<<<NB, 256, 0, stream>>>(P, D, G, edgeRow, edgePk, Wr4, Wn4, b4);
        // conv4 gather -> final BNC in d_out
        gather_kernel<true><<<NB, 256, 0, stream>>>(P, G, D, edgeRow, edgePk);
    } else {
        // ---- round-7 fallback: P = d_out (NCB scratch), G = ws buffer ----
        pool_kernel<<<NB, 256, 0, stream>>>(x, P, poolRow, poolPk);
        dense_kernel<false><<<2048, 256, 0, stream>>>(P, P, G, Wr1, Wn1, b1, nullptr);
        gather_kernel<false><<<NB, 256, 0, stream>>>(P, G, P, edgeRow, edgePk);
        dense_kernel<false><<<2048, 256, 0, stream>>>(P, P, G, Wr2, Wn2, b2, nullptr);
        gather_kernel<false><<<NB, 256, 0, stream>>>(P, G, P, edgeRow, edgePk);
        stats_kernel<<<200, 256, 0, stream>>>(P, stats);
        stats_fin<<<1, 128, 0, stream>>>(stats);
        dense_kernel<true><<<2048, 256, 0, stream>>>(P, P, G, Wr3, Wn3, b3, stats);
        gather_kernel<false><<<NB, 256, 0, stream>>>(P, G, P, edgeRow, edgePk);
        dense_kernel<false><<<2048, 256, 0, stream>>>(P, P, G, Wr4, Wn4, b4, nullptr);
        gather_kernel<false><<<NB, 256, 0, stream>>>(P, G, P, edgeRow, edgePk);
        transpose_kernel<<<NB, 256, 0, stream>>>(P, G);   // P==d_out (NCB) -> G (BNC)
        hipMemcpyAsync(D, G, BUFB, hipMemcpyDeviceToDevice, stream);
    }
}